// Round 1
// baseline (2260.903 us; speedup 1.0000x reference)
//
#include <hip/hip_runtime.h>
#include <math.h>

#define NN 50000
#define NE 800000
#define NG 500
#define NCONV 13
#define WSTRIDE 304   // 289 weights per conv, padded

// ---------------- CSR build ----------------

__global__ void zero_init_k(int* __restrict__ cursor, float* __restrict__ pooled) {
    int i = blockIdx.x * 256 + threadIdx.x;
    if (i < NN) cursor[i] = 0;
    if (i < NG * 64) pooled[i] = 0.f;
}

__global__ void count_k(const int* __restrict__ dstp, int* __restrict__ cnt) {
    int e = blockIdx.x * 256 + threadIdx.x;
    if (e >= NE) return;
    atomicAdd(cnt + dstp[e], 1);
}

__global__ __launch_bounds__(1024) void scan_k(int* __restrict__ cnt_cursor, int* __restrict__ row_start) {
    __shared__ int ss[1024];
    int t = threadIdx.x;
    const int CH = (NN + 1023) / 1024;  // 49
    int b = t * CH;
    int e = b + CH; if (e > NN) e = NN;
    int s = 0;
    for (int i = b; i < e; i++) s += cnt_cursor[i];
    ss[t] = s;
    __syncthreads();
    for (int off = 1; off < 1024; off <<= 1) {
        int add = (t >= off) ? ss[t - off] : 0;
        __syncthreads();
        ss[t] += add;
        __syncthreads();
    }
    int base = (t == 0) ? 0 : ss[t - 1];
    for (int i = b; i < e; i++) {
        int cv = cnt_cursor[i];
        row_start[i] = base;
        cnt_cursor[i] = base;  // becomes scatter cursor
        base += cv;
    }
    if (t == 0) row_start[NN] = NE;
}

__global__ void scatter_k(const int* __restrict__ srcp, const int* __restrict__ dstp,
                          int* __restrict__ cursor, int* __restrict__ csr_src, int* __restrict__ csr_eid) {
    int e = blockIdx.x * 256 + threadIdx.x;
    if (e >= NE) return;
    int p = atomicAdd(cursor + dstp[e], 1);
    csr_src[p] = srcp[e];
    csr_eid[p] = e;
}

// ---------------- edge MLPs (all 13 convs, CSR order) ----------------

__global__ void pack_weights_k(const float* __restrict__ m1W1, const float* __restrict__ m1b1,
                               const float* __restrict__ m2W1, const float* __restrict__ m2b1,
                               const float* __restrict__ hm1W, const float* __restrict__ hm1b,
                               const float* __restrict__ hm2W, const float* __restrict__ hm2b,
                               float* __restrict__ wbuf) {
    int i = blockIdx.x * 256 + threadIdx.x;
    if (i >= NCONV * 289) return;
    int cc = i / 289, r = i % 289;
    float v;
    if (r < 256)      v = cc ? hm1W[(cc - 1) * 256 + r] : m1W1[r];
    else if (r < 272) v = cc ? hm1b[(cc - 1) * 16 + (r - 256)] : m1b1[r - 256];
    else if (r < 288) v = cc ? hm2W[(cc - 1) * 16 + (r - 272)] : m2W1[r - 272];
    else              v = cc ? hm2b[cc - 1] : m2b1[0];
    wbuf[cc * WSTRIDE + r] = v;
}

__global__ __launch_bounds__(256) void edge_mlp_k(const float* __restrict__ attr, const int* __restrict__ eid_arr,
                                                  const float* __restrict__ wbuf, float* __restrict__ ew) {
    int k = blockIdx.x * 256 + threadIdx.x;
    if (k >= NE) return;
    int eid = eid_arr[k];
    const float4* a4 = (const float4*)(attr + (size_t)eid * 16);
    float4 A0 = a4[0], A1 = a4[1], A2 = a4[2], A3 = a4[3];
    float a[16] = {A0.x, A0.y, A0.z, A0.w, A1.x, A1.y, A1.z, A1.w,
                   A2.x, A2.y, A2.z, A2.w, A3.x, A3.y, A3.z, A3.w};
    for (int cc = 0; cc < NCONV; cc++) {
        const float* wb = wbuf + cc * WSTRIDE;  // uniform address -> s_load
        float hb[16];
        #pragma unroll
        for (int o = 0; o < 16; o++) hb[o] = wb[256 + o];
        #pragma unroll
        for (int i = 0; i < 16; i++) {
            float av = a[i];
            #pragma unroll
            for (int o = 0; o < 16; o++) hb[o] = fmaf(av, wb[i * 16 + o], hb[o]);
        }
        float z = wb[288];
        #pragma unroll
        for (int o = 0; o < 16; o++) {
            float hv = hb[o] > 0.f ? hb[o] : 0.f;
            z = fmaf(hv, wb[272 + o], z);
        }
        ew[(size_t)cc * NE + k] = 1.f / (1.f + __expf(-z));
    }
}

// deg = 1 + sum of incoming ew; dis = rsqrt(deg)  (deg >= 1 always)
__global__ void deg_dis_k(const int* __restrict__ row_start, const float* __restrict__ ew,
                          float* __restrict__ dis) {
    int n = blockIdx.x * 256 + threadIdx.x;
    int cc = blockIdx.y;
    if (n >= NN) return;
    int s0 = row_start[n], s1 = row_start[n + 1];
    const float* e = ew + (size_t)cc * NE;
    float s = 1.f;
    for (int k = s0; k < s1; k++) s += e[k];
    dis[cc * NN + n] = rsqrtf(s);
}

// fold dis[src] into edge weight: ew[k] *= dis[src[k]]
__global__ void prep_w_k(const int* __restrict__ csr_src, const float* __restrict__ dis,
                         float* __restrict__ ew) {
    int k = blockIdx.x * 256 + threadIdx.x;
    int cc = blockIdx.y;
    if (k >= NE) return;
    int s = csr_src[k];
    ew[(size_t)cc * NE + k] *= dis[cc * NN + s];
}

// ---------------- BN stats ----------------

#define BN_BLOCKS 250  // 200 rows each

__global__ __launch_bounds__(256) void bn_part_k(const float* __restrict__ cur, float* __restrict__ part) {
    int c = threadIdx.x & 63, rq = threadIdx.x >> 6;
    int r0 = blockIdx.x * 200;
    float s = 0.f, q = 0.f;
    for (int r = r0 + rq; r < r0 + 200; r += 4) {
        float v = cur[(size_t)r * 64 + c];
        s += v; q = fmaf(v, v, q);
    }
    __shared__ float red[512];
    red[threadIdx.x] = s; red[256 + threadIdx.x] = q;
    __syncthreads();
    if (rq == 0) {
        s = red[c] + red[64 + c] + red[128 + c] + red[192 + c];
        q = red[256 + c] + red[320 + c] + red[384 + c] + red[448 + c];
        part[blockIdx.x * 128 + c] = s;
        part[blockIdx.x * 128 + 64 + c] = q;
    }
}

__global__ void bn_final_k(const float* __restrict__ part, float* __restrict__ bnstats) {
    int c = threadIdx.x;  // 64 threads
    double s = 0.0, q = 0.0;
    for (int b = 0; b < BN_BLOCKS; b++) {
        s += (double)part[b * 128 + c];
        q += (double)part[b * 128 + 64 + c];
    }
    double mu = s / (double)NN;
    double var = q / (double)NN - mu * mu;
    if (var < 0.0) var = 0.0;
    bnstats[c] = (float)mu;
    bnstats[64 + c] = (float)(1.0 / sqrt(var + 1e-5));
}

// ---------------- GEMM: H = bn_relu(X) @ W  (one row per thread, W via s_load) ----------------

template <bool BN>
__global__ __launch_bounds__(256) void gemm_k(const float* __restrict__ X, const float* __restrict__ Wg,
                                              const float* __restrict__ bnstats, float* __restrict__ H) {
    int r = blockIdx.x * 256 + threadIdx.x;
    if (r >= NN) return;
    float acc[64];
    #pragma unroll
    for (int c = 0; c < 64; c++) acc[c] = 0.f;
    const float4* x4 = (const float4*)(X + (size_t)r * 64);
    for (int kq = 0; kq < 16; kq++) {
        float4 xv = x4[kq];
        float xs[4] = {xv.x, xv.y, xv.z, xv.w};
        #pragma unroll
        for (int j = 0; j < 4; j++) {
            int k = kq * 4 + j;
            float v = xs[j];
            if (BN) {
                v = (v - bnstats[k]) * bnstats[64 + k];
                v = v > 0.f ? v : 0.f;
            }
            const float* wr = Wg + k * 64;  // uniform -> SGPR operands
            #pragma unroll
            for (int c = 0; c < 64; c++) acc[c] = fmaf(v, wr[c], acc[c]);
        }
    }
    float4* o4 = (float4*)(H + (size_t)r * 64);
    #pragma unroll
    for (int q = 0; q < 16; q++) {
        float4 t;
        t.x = acc[4 * q]; t.y = acc[4 * q + 1]; t.z = acc[4 * q + 2]; t.w = acc[4 * q + 3];
        o4[q] = t;
    }
}

// ---------------- aggregation: one wave per node ----------------

__global__ __launch_bounds__(256) void aggregate_k(const float* __restrict__ H, const int* __restrict__ row_start,
                                                   const int* __restrict__ csr_src, const float* __restrict__ w,
                                                   const float* __restrict__ dis, const float* __restrict__ bias,
                                                   float* __restrict__ outv, float* __restrict__ S, int writeS) {
    int node = blockIdx.x * 4 + (threadIdx.x >> 6);
    int c = threadIdx.x & 63;
    if (node >= NN) return;
    int s0 = row_start[node], s1 = row_start[node + 1];
    float acc = 0.f;
    for (int k = s0; k < s1; k++) {
        int s = csr_src[k];
        acc = fmaf(H[(size_t)s * 64 + c], w[k], acc);
    }
    float dn = dis[node];
    float v = acc * dn + H[(size_t)node * 64 + c] * (dn * dn) + bias[c];
    outv[(size_t)node * 64 + c] = v;
    if (writeS) S[(size_t)node * 64 + c] = v;
}

// cur += S; S += cur_new   (float4)
__global__ void skip_k(float* __restrict__ cur, float* __restrict__ S) {
    int i = blockIdx.x * 256 + threadIdx.x;
    if (i >= NN * 16) return;
    float4* c4 = (float4*)cur;
    float4* s4 = (float4*)S;
    float4 a = c4[i], b = s4[i];
    a.x += b.x; a.y += b.y; a.z += b.z; a.w += b.w;
    c4[i] = a;
    b.x += a.x; b.y += a.y; b.z += a.z; b.w += a.w;
    s4[i] = b;
}

// relu + segment max via int atomicMax (values >= 0)
__global__ void pool_k(const float* __restrict__ cur, const int* __restrict__ batch,
                       float* __restrict__ pooled) {
    int i = blockIdx.x * 256 + threadIdx.x;
    if (i >= NN * 64) return;
    int n = i >> 6, c = i & 63;
    float v = cur[i];
    v = v > 0.f ? v : 0.f;
    atomicMax((int*)(pooled + (size_t)batch[n] * 64 + c), __float_as_int(v));
}

__global__ void final_k(const float* __restrict__ pooled, const float* __restrict__ linW,
                        const float* __restrict__ linb, float* __restrict__ outp) {
    int g = blockIdx.x, c = threadIdx.x;  // 64 threads
    float v = pooled[(size_t)g * 64 + c];
    float p0 = v * linW[c * 2 + 0];
    float p1 = v * linW[c * 2 + 1];
    #pragma unroll
    for (int off = 32; off > 0; off >>= 1) {
        p0 += __shfl_down(p0, off, 64);
        p1 += __shfl_down(p1, off, 64);
    }
    if (c == 0) {
        outp[g * 2 + 0] = p0 + linb[0];
        outp[g * 2 + 1] = p1 + linb[1];
    }
}

// ---------------- host ----------------

extern "C" void kernel_launch(void* const* d_in, const int* in_sizes, int n_in,
                              void* d_out, int out_size, void* d_ws, size_t ws_size,
                              hipStream_t stream) {
    const float* x        = (const float*)d_in[0];
    const int*   ei       = (const int*)d_in[1];
    const int*   srcp     = ei;
    const int*   dstp     = ei + NE;
    const int*   batch    = (const int*)d_in[2];
    const float* edge_attr= (const float*)d_in[4];
    const float* Wlin1    = (const float*)d_in[5];
    const float* bias1    = (const float*)d_in[6];
    const float* m1W1     = (const float*)d_in[7];
    const float* m1b1     = (const float*)d_in[8];
    const float* m2W1     = (const float*)d_in[9];
    const float* m2b1     = (const float*)d_in[10];
    const float* hWlin    = (const float*)d_in[11];
    const float* hbias    = (const float*)d_in[12];
    const float* hm1W     = (const float*)d_in[13];
    const float* hm1b     = (const float*)d_in[14];
    const float* hm2W     = (const float*)d_in[15];
    const float* hm2b     = (const float*)d_in[16];
    const float* linW     = (const float*)d_in[17];
    const float* linb     = (const float*)d_in[18];
    float* outp = (float*)d_out;

    char* ws = (char*)d_ws;
    size_t off = 0;
    auto alloc = [&](size_t bytes) -> char* {
        char* p = ws + off;
        off += (bytes + 255) & ~(size_t)255;
        return p;
    };
    int*   cursor   = (int*)alloc((size_t)NN * 4);
    int*   row_start= (int*)alloc((size_t)(NN + 1) * 4);
    int*   csr_src  = (int*)alloc((size_t)NE * 4);
    int*   csr_eid  = (int*)alloc((size_t)NE * 4);
    float* ewbuf    = (float*)alloc((size_t)NCONV * NE * 4);
    float* disbuf   = (float*)alloc((size_t)NCONV * NN * 4);
    float* hbuf     = (float*)alloc((size_t)NN * 64 * 4);
    float* curbuf   = (float*)alloc((size_t)NN * 64 * 4);
    float* Sbuf     = (float*)alloc((size_t)NN * 64 * 4);
    float* part     = (float*)alloc((size_t)BN_BLOCKS * 128 * 4);
    float* bnstats  = (float*)alloc(128 * 4);
    float* pooled   = (float*)alloc((size_t)NG * 64 * 4);
    float* wbuf     = (float*)alloc((size_t)NCONV * WSTRIDE * 4);

    const int TB = 256;
    int gN   = (NN + TB - 1) / TB;        // 196
    int gE   = (NE + TB - 1) / TB;        // 3125
    int gNC  = (NN * 64 + TB - 1) / TB;   // 12500
    int gN4  = (NN + 3) / 4;              // 12500
    int gV4  = (NN * 16 + TB - 1) / TB;   // 3125
    int gW   = (NCONV * 289 + TB - 1) / TB;

    // CSR build
    zero_init_k<<<gN, TB, 0, stream>>>(cursor, pooled);
    count_k<<<gE, TB, 0, stream>>>(dstp, cursor);
    scan_k<<<1, 1024, 0, stream>>>(cursor, row_start);
    scatter_k<<<gE, TB, 0, stream>>>(srcp, dstp, cursor, csr_src, csr_eid);

    // edge weights for all 13 convs
    pack_weights_k<<<gW, TB, 0, stream>>>(m1W1, m1b1, m2W1, m2b1, hm1W, hm1b, hm2W, hm2b, wbuf);
    edge_mlp_k<<<gE, TB, 0, stream>>>(edge_attr, csr_eid, wbuf, ewbuf);
    deg_dis_k<<<dim3(gN, NCONV), TB, 0, stream>>>(row_start, ewbuf, disbuf);
    prep_w_k<<<dim3(gE, NCONV), TB, 0, stream>>>(csr_src, disbuf, ewbuf);

    // conv 0 (no BN), then 12 hidden convs
    for (int cj = 0; cj < NCONV; cj++) {
        const float* Win  = (cj == 0) ? Wlin1 : (hWlin + (size_t)(cj - 1) * 4096);
        const float* bin  = (cj == 0) ? bias1 : (hbias + (size_t)(cj - 1) * 64);
        const float* Xin  = (cj == 0) ? x : curbuf;
        if (cj > 0) {
            bn_part_k<<<BN_BLOCKS, TB, 0, stream>>>(curbuf, part);
            bn_final_k<<<1, 64, 0, stream>>>(part, bnstats);
            gemm_k<true><<<gN, TB, 0, stream>>>(Xin, Win, bnstats, hbuf);
        } else {
            gemm_k<false><<<gN, TB, 0, stream>>>(Xin, Win, bnstats, hbuf);
        }
        aggregate_k<<<gN4, TB, 0, stream>>>(hbuf, row_start, csr_src,
                                            ewbuf + (size_t)cj * NE, disbuf + (size_t)cj * NN,
                                            bin, curbuf, Sbuf, cj == 0 ? 1 : 0);
        if (cj > 0 && (cj & 1) == 0) {  // end of each 2-conv block: cj = 2,4,6,8,10,12
            skip_k<<<gV4, TB, 0, stream>>>(curbuf, Sbuf);
        }
    }

    // readout
    pool_k<<<gNC, TB, 0, stream>>>(curbuf, batch, pooled);
    final_k<<<NG, 64, 0, stream>>>(pooled, linW, linb, outp);
}

// Round 2
// 2164.082 us; speedup vs baseline: 1.0447x; 1.0447x over previous
//
#include <hip/hip_runtime.h>
#include <math.h>

#define NN 50000
#define NE 800000
#define NG 500
#define NCONV 13
#define WSTRIDE 304   // 289 weights per conv, padded
#define SCAN_B 196    // ceil(NN/256)

// ---------------- CSR build ----------------

__global__ void zero_init_k(int* __restrict__ cursor, float* __restrict__ pooled) {
    int i = blockIdx.x * 256 + threadIdx.x;
    if (i < NN) cursor[i] = 0;
    if (i < NG * 64) pooled[i] = 0.f;
}

__global__ void count_k(const int* __restrict__ dstp, int* __restrict__ cnt) {
    int e = blockIdx.x * 256 + threadIdx.x;
    if (e >= NE) return;
    atomicAdd(cnt + dstp[e], 1);
}

// phase A: per-block sums of counts (coalesced)
__global__ __launch_bounds__(256) void scan_blocksum_k(const int* __restrict__ cnt, int* __restrict__ bsum) {
    int i = blockIdx.x * 256 + threadIdx.x;
    int v = (i < NN) ? cnt[i] : 0;
    __shared__ int red[256];
    red[threadIdx.x] = v;
    __syncthreads();
    for (int off = 128; off > 0; off >>= 1) {
        if (threadIdx.x < off) red[threadIdx.x] += red[threadIdx.x + off];
        __syncthreads();
    }
    if (threadIdx.x == 0) bsum[blockIdx.x] = red[0];
}

// phase B: exclusive scan of the 196 block sums (single tiny block)
__global__ __launch_bounds__(256) void scan_bsum_k(int* __restrict__ bsum, int* __restrict__ row_start) {
    __shared__ int ss[256];
    int t = threadIdx.x;
    int v = (t < SCAN_B) ? bsum[t] : 0;
    ss[t] = v;
    __syncthreads();
    for (int off = 1; off < 256; off <<= 1) {
        int add = (t >= off) ? ss[t - off] : 0;
        __syncthreads();
        ss[t] += add;
        __syncthreads();
    }
    if (t < SCAN_B) bsum[t] = (t == 0) ? 0 : ss[t - 1];
    if (t == 0) row_start[NN] = NE;
}

// phase C: local block scan + block offset -> row_start and scatter cursor
__global__ __launch_bounds__(256) void scan_local_k(int* __restrict__ cnt_cursor, const int* __restrict__ bsum,
                                                    int* __restrict__ row_start) {
    __shared__ int ss[256];
    int i = blockIdx.x * 256 + threadIdx.x;
    int t = threadIdx.x;
    int v = (i < NN) ? cnt_cursor[i] : 0;
    ss[t] = v;
    __syncthreads();
    for (int off = 1; off < 256; off <<= 1) {
        int add = (t >= off) ? ss[t - off] : 0;
        __syncthreads();
        ss[t] += add;
        __syncthreads();
    }
    int excl = bsum[blockIdx.x] + ((t == 0) ? 0 : ss[t - 1]);
    if (i < NN) {
        row_start[i] = excl;
        cnt_cursor[i] = excl;  // becomes scatter cursor
    }
}

__global__ void scatter_k(const int* __restrict__ srcp, const int* __restrict__ dstp,
                          int* __restrict__ cursor, int* __restrict__ csr_src, int* __restrict__ csr_eid) {
    int e = blockIdx.x * 256 + threadIdx.x;
    if (e >= NE) return;
    int p = atomicAdd(cursor + dstp[e], 1);
    csr_src[p] = srcp[e];
    csr_eid[p] = e;
}

// ---------------- edge MLPs (all 13 convs, CSR order) ----------------

__global__ void pack_weights_k(const float* __restrict__ m1W1, const float* __restrict__ m1b1,
                               const float* __restrict__ m2W1, const float* __restrict__ m2b1,
                               const float* __restrict__ hm1W, const float* __restrict__ hm1b,
                               const float* __restrict__ hm2W, const float* __restrict__ hm2b,
                               float* __restrict__ wbuf) {
    int i = blockIdx.x * 256 + threadIdx.x;
    if (i >= NCONV * 289) return;
    int cc = i / 289, r = i % 289;
    float v;
    if (r < 256)      v = cc ? hm1W[(cc - 1) * 256 + r] : m1W1[r];
    else if (r < 272) v = cc ? hm1b[(cc - 1) * 16 + (r - 256)] : m1b1[r - 256];
    else if (r < 288) v = cc ? hm2W[(cc - 1) * 16 + (r - 272)] : m2W1[r - 272];
    else              v = cc ? hm2b[cc - 1] : m2b1[0];
    wbuf[cc * WSTRIDE + r] = v;
}

__global__ __launch_bounds__(256) void edge_mlp_k(const float* __restrict__ attr, const int* __restrict__ eid_arr,
                                                  const float* __restrict__ wbuf, float* __restrict__ ew) {
    int k = blockIdx.x * 256 + threadIdx.x;
    if (k >= NE) return;
    int eid = eid_arr[k];
    const float4* a4 = (const float4*)(attr + (size_t)eid * 16);
    float4 A0 = a4[0], A1 = a4[1], A2 = a4[2], A3 = a4[3];
    float a[16] = {A0.x, A0.y, A0.z, A0.w, A1.x, A1.y, A1.z, A1.w,
                   A2.x, A2.y, A2.z, A2.w, A3.x, A3.y, A3.z, A3.w};
    for (int cc = 0; cc < NCONV; cc++) {
        const float* wb = wbuf + cc * WSTRIDE;  // uniform address -> s_load
        float hb[16];
        #pragma unroll
        for (int o = 0; o < 16; o++) hb[o] = wb[256 + o];
        #pragma unroll
        for (int i = 0; i < 16; i++) {
            float av = a[i];
            #pragma unroll
            for (int o = 0; o < 16; o++) hb[o] = fmaf(av, wb[i * 16 + o], hb[o]);
        }
        float z = wb[288];
        #pragma unroll
        for (int o = 0; o < 16; o++) {
            float hv = hb[o] > 0.f ? hb[o] : 0.f;
            z = fmaf(hv, wb[272 + o], z);
        }
        ew[(size_t)cc * NE + k] = 1.f / (1.f + __expf(-z));
    }
}

// deg = 1 + sum of incoming ew; dis = rsqrt(deg)  (deg >= 1 always)
__global__ void deg_dis_k(const int* __restrict__ row_start, const float* __restrict__ ew,
                          float* __restrict__ dis) {
    int n = blockIdx.x * 256 + threadIdx.x;
    int cc = blockIdx.y;
    if (n >= NN) return;
    int s0 = row_start[n], s1 = row_start[n + 1];
    const float* e = ew + (size_t)cc * NE;
    float s = 1.f;
    for (int k = s0; k < s1; k++) s += e[k];
    dis[cc * NN + n] = rsqrtf(s);
}

// fold dis[src] into edge weight: ew[k] *= dis[src[k]]
__global__ void prep_w_k(const int* __restrict__ csr_src, const float* __restrict__ dis,
                         float* __restrict__ ew) {
    int k = blockIdx.x * 256 + threadIdx.x;
    int cc = blockIdx.y;
    if (k >= NE) return;
    int s = csr_src[k];
    ew[(size_t)cc * NE + k] *= dis[cc * NN + s];
}

// ---------------- BN stats ----------------

#define BN_BLOCKS 250  // 200 rows each

__global__ __launch_bounds__(256) void bn_part_k(const float* __restrict__ cur, float* __restrict__ part) {
    int c = threadIdx.x & 63, rq = threadIdx.x >> 6;
    int r0 = blockIdx.x * 200;
    float s = 0.f, q = 0.f;
    for (int r = r0 + rq; r < r0 + 200; r += 4) {
        float v = cur[(size_t)r * 64 + c];
        s += v; q = fmaf(v, v, q);
    }
    __shared__ float red[512];
    red[threadIdx.x] = s; red[256 + threadIdx.x] = q;
    __syncthreads();
    if (rq == 0) {
        s = red[c] + red[64 + c] + red[128 + c] + red[192 + c];
        q = red[256 + c] + red[320 + c] + red[384 + c] + red[448 + c];
        part[blockIdx.x * 128 + c] = s;
        part[blockIdx.x * 128 + 64 + c] = q;
    }
}

__global__ void bn_final_k(const float* __restrict__ part, float* __restrict__ bnstats) {
    int c = threadIdx.x;  // 64 threads
    double s = 0.0, q = 0.0;
    for (int b = 0; b < BN_BLOCKS; b++) {
        s += (double)part[b * 128 + c];
        q += (double)part[b * 128 + 64 + c];
    }
    double mu = s / (double)NN;
    double var = q / (double)NN - mu * mu;
    if (var < 0.0) var = 0.0;
    bnstats[c] = (float)mu;
    bnstats[64 + c] = (float)(1.0 / sqrt(var + 1e-5));
}

// ---------------- GEMM: H = bn_relu(X) @ W  (one row per thread, W via s_load) ----------------

template <bool BN>
__global__ __launch_bounds__(256) void gemm_k(const float* __restrict__ X, const float* __restrict__ Wg,
                                              const float* __restrict__ bnstats, float* __restrict__ H) {
    int r = blockIdx.x * 256 + threadIdx.x;
    if (r >= NN) return;
    float acc[64];
    #pragma unroll
    for (int c = 0; c < 64; c++) acc[c] = 0.f;
    const float4* x4 = (const float4*)(X + (size_t)r * 64);
    for (int kq = 0; kq < 16; kq++) {
        float4 xv = x4[kq];
        float xs[4] = {xv.x, xv.y, xv.z, xv.w};
        #pragma unroll
        for (int j = 0; j < 4; j++) {
            int k = kq * 4 + j;
            float v = xs[j];
            if (BN) {
                v = (v - bnstats[k]) * bnstats[64 + k];
                v = v > 0.f ? v : 0.f;
            }
            const float* wr = Wg + k * 64;  // uniform -> SGPR operands
            #pragma unroll
            for (int c = 0; c < 64; c++) acc[c] = fmaf(v, wr[c], acc[c]);
        }
    }
    float4* o4 = (float4*)(H + (size_t)r * 64);
    #pragma unroll
    for (int q = 0; q < 16; q++) {
        float4 t;
        t.x = acc[4 * q]; t.y = acc[4 * q + 1]; t.z = acc[4 * q + 2]; t.w = acc[4 * q + 3];
        o4[q] = t;
    }
}

// ---------------- aggregation: one wave per node ----------------

__global__ __launch_bounds__(256) void aggregate_k(const float* __restrict__ H, const int* __restrict__ row_start,
                                                   const int* __restrict__ csr_src, const float* __restrict__ w,
                                                   const float* __restrict__ dis, const float* __restrict__ bias,
                                                   float* __restrict__ outv, float* __restrict__ S, int writeS) {
    int node = blockIdx.x * 4 + (threadIdx.x >> 6);
    int c = threadIdx.x & 63;
    if (node >= NN) return;
    int s0 = row_start[node], s1 = row_start[node + 1];
    float acc = 0.f;
    for (int k = s0; k < s1; k++) {
        int s = csr_src[k];
        acc = fmaf(H[(size_t)s * 64 + c], w[k], acc);
    }
    float dn = dis[node];
    float v = acc * dn + H[(size_t)node * 64 + c] * (dn * dn) + bias[c];
    outv[(size_t)node * 64 + c] = v;
    if (writeS) S[(size_t)node * 64 + c] = v;
}

// cur += S; S += cur_new   (float4)
__global__ void skip_k(float* __restrict__ cur, float* __restrict__ S) {
    int i = blockIdx.x * 256 + threadIdx.x;
    if (i >= NN * 16) return;
    float4* c4 = (float4*)cur;
    float4* s4 = (float4*)S;
    float4 a = c4[i], b = s4[i];
    a.x += b.x; a.y += b.y; a.z += b.z; a.w += b.w;
    c4[i] = a;
    b.x += a.x; b.y += a.y; b.z += a.z; b.w += a.w;
    s4[i] = b;
}

// relu + segment max via int atomicMax (values >= 0)
__global__ void pool_k(const float* __restrict__ cur, const int* __restrict__ batch,
                       float* __restrict__ pooled) {
    int i = blockIdx.x * 256 + threadIdx.x;
    if (i >= NN * 64) return;
    int n = i >> 6, c = i & 63;
    float v = cur[i];
    v = v > 0.f ? v : 0.f;
    atomicMax((int*)(pooled + (size_t)batch[n] * 64 + c), __float_as_int(v));
}

__global__ void final_k(const float* __restrict__ pooled, const float* __restrict__ linW,
                        const float* __restrict__ linb, float* __restrict__ outp) {
    int g = blockIdx.x, c = threadIdx.x;  // 64 threads
    float v = pooled[(size_t)g * 64 + c];
    float p0 = v * linW[c * 2 + 0];
    float p1 = v * linW[c * 2 + 1];
    #pragma unroll
    for (int off = 32; off > 0; off >>= 1) {
        p0 += __shfl_down(p0, off, 64);
        p1 += __shfl_down(p1, off, 64);
    }
    if (c == 0) {
        outp[g * 2 + 0] = p0 + linb[0];
        outp[g * 2 + 1] = p1 + linb[1];
    }
}

// ---------------- host ----------------

extern "C" void kernel_launch(void* const* d_in, const int* in_sizes, int n_in,
                              void* d_out, int out_size, void* d_ws, size_t ws_size,
                              hipStream_t stream) {
    const float* x        = (const float*)d_in[0];
    const int*   ei       = (const int*)d_in[1];
    const int*   srcp     = ei;
    const int*   dstp     = ei + NE;
    const int*   batch    = (const int*)d_in[2];
    const float* edge_attr= (const float*)d_in[4];
    const float* Wlin1    = (const float*)d_in[5];
    const float* bias1    = (const float*)d_in[6];
    const float* m1W1     = (const float*)d_in[7];
    const float* m1b1     = (const float*)d_in[8];
    const float* m2W1     = (const float*)d_in[9];
    const float* m2b1     = (const float*)d_in[10];
    const float* hWlin    = (const float*)d_in[11];
    const float* hbias    = (const float*)d_in[12];
    const float* hm1W     = (const float*)d_in[13];
    const float* hm1b     = (const float*)d_in[14];
    const float* hm2W     = (const float*)d_in[15];
    const float* hm2b     = (const float*)d_in[16];
    const float* linW     = (const float*)d_in[17];
    const float* linb     = (const float*)d_in[18];
    float* outp = (float*)d_out;

    char* ws = (char*)d_ws;
    size_t off = 0;
    auto alloc = [&](size_t bytes) -> char* {
        char* p = ws + off;
        off += (bytes + 255) & ~(size_t)255;
        return p;
    };
    int*   cursor   = (int*)alloc((size_t)NN * 4);
    int*   row_start= (int*)alloc((size_t)(NN + 1) * 4);
    int*   csr_src  = (int*)alloc((size_t)NE * 4);
    int*   csr_eid  = (int*)alloc((size_t)NE * 4);
    float* ewbuf    = (float*)alloc((size_t)NCONV * NE * 4);
    float* disbuf   = (float*)alloc((size_t)NCONV * NN * 4);
    float* hbuf     = (float*)alloc((size_t)NN * 64 * 4);
    float* curbuf   = (float*)alloc((size_t)NN * 64 * 4);
    float* Sbuf     = (float*)alloc((size_t)NN * 64 * 4);
    float* part     = (float*)alloc((size_t)BN_BLOCKS * 128 * 4);
    float* bnstats  = (float*)alloc(128 * 4);
    float* pooled   = (float*)alloc((size_t)NG * 64 * 4);
    float* wbuf     = (float*)alloc((size_t)NCONV * WSTRIDE * 4);
    int*   bsum     = (int*)alloc((size_t)SCAN_B * 4);

    const int TB = 256;
    int gN   = (NN + TB - 1) / TB;        // 196
    int gE   = (NE + TB - 1) / TB;        // 3125
    int gNC  = (NN * 64 + TB - 1) / TB;   // 12500
    int gN4  = (NN + 3) / 4;              // 12500
    int gV4  = (NN * 16 + TB - 1) / TB;   // 3125
    int gW   = (NCONV * 289 + TB - 1) / TB;

    // CSR build (hierarchical scan: 110us single-block scan -> ~10us total)
    zero_init_k<<<gN, TB, 0, stream>>>(cursor, pooled);
    count_k<<<gE, TB, 0, stream>>>(dstp, cursor);
    scan_blocksum_k<<<SCAN_B, TB, 0, stream>>>(cursor, bsum);
    scan_bsum_k<<<1, TB, 0, stream>>>(bsum, row_start);
    scan_local_k<<<SCAN_B, TB, 0, stream>>>(cursor, bsum, row_start);
    scatter_k<<<gE, TB, 0, stream>>>(srcp, dstp, cursor, csr_src, csr_eid);

    // edge weights for all 13 convs
    pack_weights_k<<<gW, TB, 0, stream>>>(m1W1, m1b1, m2W1, m2b1, hm1W, hm1b, hm2W, hm2b, wbuf);
    edge_mlp_k<<<gE, TB, 0, stream>>>(edge_attr, csr_eid, wbuf, ewbuf);
    deg_dis_k<<<dim3(gN, NCONV), TB, 0, stream>>>(row_start, ewbuf, disbuf);
    prep_w_k<<<dim3(gE, NCONV), TB, 0, stream>>>(csr_src, disbuf, ewbuf);

    // conv 0 (no BN), then 12 hidden convs
    for (int cj = 0; cj < NCONV; cj++) {
        const float* Win  = (cj == 0) ? Wlin1 : (hWlin + (size_t)(cj - 1) * 4096);
        const float* bin  = (cj == 0) ? bias1 : (hbias + (size_t)(cj - 1) * 64);
        const float* Xin  = (cj == 0) ? x : curbuf;
        if (cj > 0) {
            bn_part_k<<<BN_BLOCKS, TB, 0, stream>>>(curbuf, part);
            bn_final_k<<<1, 64, 0, stream>>>(part, bnstats);
            gemm_k<true><<<gN, TB, 0, stream>>>(Xin, Win, bnstats, hbuf);
        } else {
            gemm_k<false><<<gN, TB, 0, stream>>>(Xin, Win, bnstats, hbuf);
        }
        aggregate_k<<<gN4, TB, 0, stream>>>(hbuf, row_start, csr_src,
                                            ewbuf + (size_t)cj * NE, disbuf + (size_t)cj * NN,
                                            bin, curbuf, Sbuf, cj == 0 ? 1 : 0);
        if (cj > 0 && (cj & 1) == 0) {  // end of each 2-conv block: cj = 2,4,6,8,10,12
            skip_k<<<gV4, TB, 0, stream>>>(curbuf, Sbuf);
        }
    }

    // readout
    pool_k<<<gNC, TB, 0, stream>>>(curbuf, batch, pooled);
    final_k<<<NG, 64, 0, stream>>>(pooled, linW, linb, outp);
}

// Round 3
// 1910.627 us; speedup vs baseline: 1.1833x; 1.1327x over previous
//
#include <hip/hip_runtime.h>
#include <math.h>

#define NN 50000
#define NE 800000
#define NG 500
#define NCONV 13
#define WSTRIDE 304   // 289 weights per conv, padded
#define SCAN_B 196    // ceil(NN/256)

// ---------------- CSR build ----------------

__global__ void zero_init_k(int* __restrict__ cursor, float* __restrict__ pooled) {
    int i = blockIdx.x * 256 + threadIdx.x;
    if (i < NN) cursor[i] = 0;
    if (i < NG * 64) pooled[i] = 0.f;
}

__global__ void count_k(const int* __restrict__ dstp, int* __restrict__ cnt) {
    int e = blockIdx.x * 256 + threadIdx.x;
    if (e >= NE) return;
    atomicAdd(cnt + dstp[e], 1);
}

// phase A: per-block sums of counts (coalesced)
__global__ __launch_bounds__(256) void scan_blocksum_k(const int* __restrict__ cnt, int* __restrict__ bsum) {
    int i = blockIdx.x * 256 + threadIdx.x;
    int v = (i < NN) ? cnt[i] : 0;
    __shared__ int red[256];
    red[threadIdx.x] = v;
    __syncthreads();
    for (int off = 128; off > 0; off >>= 1) {
        if (threadIdx.x < off) red[threadIdx.x] += red[threadIdx.x + off];
        __syncthreads();
    }
    if (threadIdx.x == 0) bsum[blockIdx.x] = red[0];
}

// phase B: exclusive scan of the 196 block sums (single tiny block)
__global__ __launch_bounds__(256) void scan_bsum_k(int* __restrict__ bsum, int* __restrict__ row_start) {
    __shared__ int ss[256];
    int t = threadIdx.x;
    int v = (t < SCAN_B) ? bsum[t] : 0;
    ss[t] = v;
    __syncthreads();
    for (int off = 1; off < 256; off <<= 1) {
        int add = (t >= off) ? ss[t - off] : 0;
        __syncthreads();
        ss[t] += add;
        __syncthreads();
    }
    if (t < SCAN_B) bsum[t] = (t == 0) ? 0 : ss[t - 1];
    if (t == 0) row_start[NN] = NE;
}

// phase C: local block scan + block offset -> row_start and scatter cursor
__global__ __launch_bounds__(256) void scan_local_k(int* __restrict__ cnt_cursor, const int* __restrict__ bsum,
                                                    int* __restrict__ row_start) {
    __shared__ int ss[256];
    int i = blockIdx.x * 256 + threadIdx.x;
    int t = threadIdx.x;
    int v = (i < NN) ? cnt_cursor[i] : 0;
    ss[t] = v;
    __syncthreads();
    for (int off = 1; off < 256; off <<= 1) {
        int add = (t >= off) ? ss[t - off] : 0;
        __syncthreads();
        ss[t] += add;
        __syncthreads();
    }
    int excl = bsum[blockIdx.x] + ((t == 0) ? 0 : ss[t - 1]);
    if (i < NN) {
        row_start[i] = excl;
        cnt_cursor[i] = excl;  // becomes scatter cursor
    }
}

__global__ void scatter_k(const int* __restrict__ srcp, const int* __restrict__ dstp,
                          int* __restrict__ cursor, int* __restrict__ csr_src, int* __restrict__ csr_eid) {
    int e = blockIdx.x * 256 + threadIdx.x;
    if (e >= NE) return;
    int p = atomicAdd(cursor + dstp[e], 1);
    csr_src[p] = srcp[e];
    csr_eid[p] = e;
}

// ---------------- edge MLPs (all 13 convs, CSR order) ----------------

__global__ void pack_weights_k(const float* __restrict__ m1W1, const float* __restrict__ m1b1,
                               const float* __restrict__ m2W1, const float* __restrict__ m2b1,
                               const float* __restrict__ hm1W, const float* __restrict__ hm1b,
                               const float* __restrict__ hm2W, const float* __restrict__ hm2b,
                               float* __restrict__ wbuf) {
    int i = blockIdx.x * 256 + threadIdx.x;
    if (i >= NCONV * 289) return;
    int cc = i / 289, r = i % 289;
    float v;
    if (r < 256)      v = cc ? hm1W[(cc - 1) * 256 + r] : m1W1[r];
    else if (r < 272) v = cc ? hm1b[(cc - 1) * 16 + (r - 256)] : m1b1[r - 256];
    else if (r < 288) v = cc ? hm2W[(cc - 1) * 16 + (r - 272)] : m2W1[r - 272];
    else              v = cc ? hm2b[cc - 1] : m2b1[0];
    wbuf[cc * WSTRIDE + r] = v;
}

// __launch_bounds__(256,4): allow ~128 VGPRs so a[16]+hb[16] stay register-resident
// (at the default the compiler throttled to 28 VGPRs and re-gathered attr per conv)
__global__ __launch_bounds__(256, 4) void edge_mlp_k(const float* __restrict__ attr, const int* __restrict__ eid_arr,
                                                     const float* __restrict__ wbuf, float* __restrict__ ew) {
    int k = blockIdx.x * 256 + threadIdx.x;
    if (k >= NE) return;
    int eid = eid_arr[k];
    const float4* a4 = (const float4*)(attr + (size_t)eid * 16);
    float4 A0 = a4[0], A1 = a4[1], A2 = a4[2], A3 = a4[3];
    float a[16] = {A0.x, A0.y, A0.z, A0.w, A1.x, A1.y, A1.z, A1.w,
                   A2.x, A2.y, A2.z, A2.w, A3.x, A3.y, A3.z, A3.w};
    for (int cc = 0; cc < NCONV; cc++) {
        const float* wb = wbuf + cc * WSTRIDE;  // uniform address -> s_load
        float hb[16];
        #pragma unroll
        for (int o = 0; o < 16; o++) hb[o] = wb[256 + o];
        #pragma unroll
        for (int i = 0; i < 16; i++) {
            float av = a[i];
            #pragma unroll
            for (int o = 0; o < 16; o++) hb[o] = fmaf(av, wb[i * 16 + o], hb[o]);
        }
        float z = wb[288];
        #pragma unroll
        for (int o = 0; o < 16; o++) {
            float hv = hb[o] > 0.f ? hb[o] : 0.f;
            z = fmaf(hv, wb[272 + o], z);
        }
        ew[(size_t)cc * NE + k] = 1.f / (1.f + __expf(-z));
    }
}

// deg = 1 + sum of incoming ew; dis = rsqrt(deg)  (deg >= 1 always)
__global__ void deg_dis_k(const int* __restrict__ row_start, const float* __restrict__ ew,
                          float* __restrict__ dis) {
    int n = blockIdx.x * 256 + threadIdx.x;
    int cc = blockIdx.y;
    if (n >= NN) return;
    int s0 = row_start[n], s1 = row_start[n + 1];
    const float* e = ew + (size_t)cc * NE;
    float s = 1.f;
    for (int k = s0; k < s1; k++) s += e[k];
    dis[cc * NN + n] = rsqrtf(s);
}

// ---------------- BN stats ----------------

#define BN_BLOCKS 250  // 200 rows each

__global__ __launch_bounds__(256) void bn_part_k(const float* __restrict__ cur, float* __restrict__ part) {
    int c = threadIdx.x & 63, rq = threadIdx.x >> 6;
    int r0 = blockIdx.x * 200;
    float s = 0.f, q = 0.f;
    for (int r = r0 + rq; r < r0 + 200; r += 4) {
        float v = cur[(size_t)r * 64 + c];
        s += v; q = fmaf(v, v, q);
    }
    __shared__ float red[512];
    red[threadIdx.x] = s; red[256 + threadIdx.x] = q;
    __syncthreads();
    if (rq == 0) {
        s = red[c] + red[64 + c] + red[128 + c] + red[192 + c];
        q = red[256 + c] + red[320 + c] + red[384 + c] + red[448 + c];
        part[blockIdx.x * 128 + c] = s;
        part[blockIdx.x * 128 + 64 + c] = q;
    }
}

__global__ void bn_final_k(const float* __restrict__ part, float* __restrict__ bnstats) {
    int c = threadIdx.x;  // 64 threads
    double s = 0.0, q = 0.0;
    for (int b = 0; b < BN_BLOCKS; b++) {
        s += (double)part[b * 128 + c];
        q += (double)part[b * 128 + 64 + c];
    }
    double mu = s / (double)NN;
    double var = q / (double)NN - mu * mu;
    if (var < 0.0) var = 0.0;
    bnstats[c] = (float)mu;
    bnstats[64 + c] = (float)(1.0 / sqrt(var + 1e-5));
}

// ---------------- GEMM: H = bn_relu(X) @ W  (one row per thread, W via s_load) ----------------

template <bool BN>
__global__ __launch_bounds__(256) void gemm_k(const float* __restrict__ X, const float* __restrict__ Wg,
                                              const float* __restrict__ bnstats, float* __restrict__ H) {
    int r = blockIdx.x * 256 + threadIdx.x;
    if (r >= NN) return;
    float acc[64];
    #pragma unroll
    for (int c = 0; c < 64; c++) acc[c] = 0.f;
    const float4* x4 = (const float4*)(X + (size_t)r * 64);
    for (int kq = 0; kq < 16; kq++) {
        float4 xv = x4[kq];
        float xs[4] = {xv.x, xv.y, xv.z, xv.w};
        #pragma unroll
        for (int j = 0; j < 4; j++) {
            int k = kq * 4 + j;
            float v = xs[j];
            if (BN) {
                v = (v - bnstats[k]) * bnstats[64 + k];
                v = v > 0.f ? v : 0.f;
            }
            const float* wr = Wg + k * 64;  // uniform -> SGPR operands
            #pragma unroll
            for (int c = 0; c < 64; c++) acc[c] = fmaf(v, wr[c], acc[c]);
        }
    }
    float4* o4 = (float4*)(H + (size_t)r * 64);
    #pragma unroll
    for (int q = 0; q < 16; q++) {
        float4 t;
        t.x = acc[4 * q]; t.y = acc[4 * q + 1]; t.z = acc[4 * q + 2]; t.w = acc[4 * q + 3];
        o4[q] = t;
    }
}

// ---------------- aggregation: one wave per node, dis[src] folded in ----------------
// MODE 0: outv = v                          (odd cj, mid-block)
// MODE 1: outv = v; S = v                   (cj == 0)
// MODE 2: v2 = v + S; outv = v2; S += v2    (end of block, cj = 2,4,6,8,10)
// MODE 3: MODE 2 + relu + pooled atomicMax  (cj == 12, final conv)

template <int MODE>
__global__ __launch_bounds__(256) void aggregate_k(const float* __restrict__ H, const int* __restrict__ row_start,
                                                   const int* __restrict__ csr_src, const float* __restrict__ w,
                                                   const float* __restrict__ dis, const float* __restrict__ bias,
                                                   float* __restrict__ outv, float* __restrict__ S,
                                                   const int* __restrict__ batch, float* __restrict__ pooled) {
    int node = blockIdx.x * 4 + (threadIdx.x >> 6);
    int c = threadIdx.x & 63;
    if (node >= NN) return;
    int s0 = row_start[node], s1 = row_start[node + 1];
    float acc0 = 0.f, acc1 = 0.f;
    int k = s0;
    for (; k + 1 < s1; k += 2) {
        int sa = csr_src[k], sb = csr_src[k + 1];
        float wa = w[k] * dis[sa];
        float wb = w[k + 1] * dis[sb];
        acc0 = fmaf(H[(size_t)sa * 64 + c], wa, acc0);
        acc1 = fmaf(H[(size_t)sb * 64 + c], wb, acc1);
    }
    if (k < s1) {
        int sa = csr_src[k];
        acc0 = fmaf(H[(size_t)sa * 64 + c], w[k] * dis[sa], acc0);
    }
    float dn = dis[node];
    float v = (acc0 + acc1) * dn + H[(size_t)node * 64 + c] * (dn * dn) + bias[c];
    size_t oi = (size_t)node * 64 + c;
    if (MODE == 0) {
        outv[oi] = v;
    } else if (MODE == 1) {
        outv[oi] = v;
        S[oi] = v;
    } else {
        float s = S[oi];
        float v2 = v + s;
        outv[oi] = v2;
        S[oi] = s + v2;
        if (MODE == 3) {
            float r = v2 > 0.f ? v2 : 0.f;
            atomicMax((int*)(pooled + (size_t)batch[node] * 64 + c), __float_as_int(r));
        }
    }
}

__global__ void final_k(const float* __restrict__ pooled, const float* __restrict__ linW,
                        const float* __restrict__ linb, float* __restrict__ outp) {
    int g = blockIdx.x, c = threadIdx.x;  // 64 threads
    float v = pooled[(size_t)g * 64 + c];
    float p0 = v * linW[c * 2 + 0];
    float p1 = v * linW[c * 2 + 1];
    #pragma unroll
    for (int off = 32; off > 0; off >>= 1) {
        p0 += __shfl_down(p0, off, 64);
        p1 += __shfl_down(p1, off, 64);
    }
    if (c == 0) {
        outp[g * 2 + 0] = p0 + linb[0];
        outp[g * 2 + 1] = p1 + linb[1];
    }
}

// ---------------- host ----------------

extern "C" void kernel_launch(void* const* d_in, const int* in_sizes, int n_in,
                              void* d_out, int out_size, void* d_ws, size_t ws_size,
                              hipStream_t stream) {
    const float* x        = (const float*)d_in[0];
    const int*   ei       = (const int*)d_in[1];
    const int*   srcp     = ei;
    const int*   dstp     = ei + NE;
    const int*   batch    = (const int*)d_in[2];
    const float* edge_attr= (const float*)d_in[4];
    const float* Wlin1    = (const float*)d_in[5];
    const float* bias1    = (const float*)d_in[6];
    const float* m1W1     = (const float*)d_in[7];
    const float* m1b1     = (const float*)d_in[8];
    const float* m2W1     = (const float*)d_in[9];
    const float* m2b1     = (const float*)d_in[10];
    const float* hWlin    = (const float*)d_in[11];
    const float* hbias    = (const float*)d_in[12];
    const float* hm1W     = (const float*)d_in[13];
    const float* hm1b     = (const float*)d_in[14];
    const float* hm2W     = (const float*)d_in[15];
    const float* hm2b     = (const float*)d_in[16];
    const float* linW     = (const float*)d_in[17];
    const float* linb     = (const float*)d_in[18];
    float* outp = (float*)d_out;

    char* ws = (char*)d_ws;
    size_t off = 0;
    auto alloc = [&](size_t bytes) -> char* {
        char* p = ws + off;
        off += (bytes + 255) & ~(size_t)255;
        return p;
    };
    int*   cursor   = (int*)alloc((size_t)NN * 4);
    int*   row_start= (int*)alloc((size_t)(NN + 1) * 4);
    int*   csr_src  = (int*)alloc((size_t)NE * 4);
    int*   csr_eid  = (int*)alloc((size_t)NE * 4);
    float* ewbuf    = (float*)alloc((size_t)NCONV * NE * 4);
    float* disbuf   = (float*)alloc((size_t)NCONV * NN * 4);
    float* hbuf     = (float*)alloc((size_t)NN * 64 * 4);
    float* curbuf   = (float*)alloc((size_t)NN * 64 * 4);
    float* Sbuf     = (float*)alloc((size_t)NN * 64 * 4);
    float* part     = (float*)alloc((size_t)BN_BLOCKS * 128 * 4);
    float* bnstats  = (float*)alloc(128 * 4);
    float* pooled   = (float*)alloc((size_t)NG * 64 * 4);
    float* wbuf     = (float*)alloc((size_t)NCONV * WSTRIDE * 4);
    int*   bsum     = (int*)alloc((size_t)SCAN_B * 4);

    const int TB = 256;
    int gN   = (NN + TB - 1) / TB;        // 196
    int gE   = (NE + TB - 1) / TB;        // 3125
    int gN4  = (NN + 3) / 4;              // 12500
    int gW   = (NCONV * 289 + TB - 1) / TB;

    // CSR build
    zero_init_k<<<gN, TB, 0, stream>>>(cursor, pooled);
    count_k<<<gE, TB, 0, stream>>>(dstp, cursor);
    scan_blocksum_k<<<SCAN_B, TB, 0, stream>>>(cursor, bsum);
    scan_bsum_k<<<1, TB, 0, stream>>>(bsum, row_start);
    scan_local_k<<<SCAN_B, TB, 0, stream>>>(cursor, bsum, row_start);
    scatter_k<<<gE, TB, 0, stream>>>(srcp, dstp, cursor, csr_src, csr_eid);

    // edge weights for all 13 convs (raw sigmoid; dis folded in at aggregate time)
    pack_weights_k<<<gW, TB, 0, stream>>>(m1W1, m1b1, m2W1, m2b1, hm1W, hm1b, hm2W, hm2b, wbuf);
    edge_mlp_k<<<gE, TB, 0, stream>>>(edge_attr, csr_eid, wbuf, ewbuf);
    deg_dis_k<<<dim3(gN, NCONV), TB, 0, stream>>>(row_start, ewbuf, disbuf);

    // conv 0 (no BN), then 12 hidden convs
    for (int cj = 0; cj < NCONV; cj++) {
        const float* Win  = (cj == 0) ? Wlin1 : (hWlin + (size_t)(cj - 1) * 4096);
        const float* bin  = (cj == 0) ? bias1 : (hbias + (size_t)(cj - 1) * 64);
        const float* Xin  = (cj == 0) ? x : curbuf;
        if (cj > 0) {
            bn_part_k<<<BN_BLOCKS, TB, 0, stream>>>(curbuf, part);
            bn_final_k<<<1, 64, 0, stream>>>(part, bnstats);
            gemm_k<true><<<gN, TB, 0, stream>>>(Xin, Win, bnstats, hbuf);
        } else {
            gemm_k<false><<<gN, TB, 0, stream>>>(Xin, Win, bnstats, hbuf);
        }
        const float* wcc = ewbuf + (size_t)cj * NE;
        const float* dcc = disbuf + (size_t)cj * NN;
        if (cj == 0)
            aggregate_k<1><<<gN4, TB, 0, stream>>>(hbuf, row_start, csr_src, wcc, dcc, bin, curbuf, Sbuf, batch, pooled);
        else if (cj == 12)
            aggregate_k<3><<<gN4, TB, 0, stream>>>(hbuf, row_start, csr_src, wcc, dcc, bin, curbuf, Sbuf, batch, pooled);
        else if ((cj & 1) == 0)
            aggregate_k<2><<<gN4, TB, 0, stream>>>(hbuf, row_start, csr_src, wcc, dcc, bin, curbuf, Sbuf, batch, pooled);
        else
            aggregate_k<0><<<gN4, TB, 0, stream>>>(hbuf, row_start, csr_src, wcc, dcc, bin, curbuf, Sbuf, batch, pooled);
    }

    // readout
    final_k<<<NG, 64, 0, stream>>>(pooled, linW, linb, outp);
}

// Round 4
// 1450.844 us; speedup vs baseline: 1.5583x; 1.3169x over previous
//
#include <hip/hip_runtime.h>
#include <math.h>

#define NN 50000
#define NE 800000
#define NG 500
#define NCONV 13
#define WSTRIDE 304   // 289 weights per conv, padded
#define SCAN_B 196    // ceil(NN/256)

// ---------------- CSR build ----------------

__global__ void zero_init_k(int* __restrict__ cursor, float* __restrict__ pooled) {
    int i = blockIdx.x * 256 + threadIdx.x;
    if (i < NN) cursor[i] = 0;
    if (i < NG * 64) pooled[i] = 0.f;
}

__global__ void count_k(const int* __restrict__ dstp, int* __restrict__ cnt) {
    int e = blockIdx.x * 256 + threadIdx.x;
    if (e >= NE) return;
    atomicAdd(cnt + dstp[e], 1);
}

// phase A: per-block sums of counts (coalesced)
__global__ __launch_bounds__(256) void scan_blocksum_k(const int* __restrict__ cnt, int* __restrict__ bsum) {
    int i = blockIdx.x * 256 + threadIdx.x;
    int v = (i < NN) ? cnt[i] : 0;
    __shared__ int red[256];
    red[threadIdx.x] = v;
    __syncthreads();
    for (int off = 128; off > 0; off >>= 1) {
        if (threadIdx.x < off) red[threadIdx.x] += red[threadIdx.x + off];
        __syncthreads();
    }
    if (threadIdx.x == 0) bsum[blockIdx.x] = red[0];
}

// phase B: exclusive scan of the 196 block sums (single tiny block)
__global__ __launch_bounds__(256) void scan_bsum_k(int* __restrict__ bsum, int* __restrict__ row_start) {
    __shared__ int ss[256];
    int t = threadIdx.x;
    int v = (t < SCAN_B) ? bsum[t] : 0;
    ss[t] = v;
    __syncthreads();
    for (int off = 1; off < 256; off <<= 1) {
        int add = (t >= off) ? ss[t - off] : 0;
        __syncthreads();
        ss[t] += add;
        __syncthreads();
    }
    if (t < SCAN_B) bsum[t] = (t == 0) ? 0 : ss[t - 1];
    if (t == 0) row_start[NN] = NE;
}

// phase C: local block scan + block offset -> row_start and scatter cursor
__global__ __launch_bounds__(256) void scan_local_k(int* __restrict__ cnt_cursor, const int* __restrict__ bsum,
                                                    int* __restrict__ row_start) {
    __shared__ int ss[256];
    int i = blockIdx.x * 256 + threadIdx.x;
    int t = threadIdx.x;
    int v = (i < NN) ? cnt_cursor[i] : 0;
    ss[t] = v;
    __syncthreads();
    for (int off = 1; off < 256; off <<= 1) {
        int add = (t >= off) ? ss[t - off] : 0;
        __syncthreads();
        ss[t] += add;
        __syncthreads();
    }
    int excl = bsum[blockIdx.x] + ((t == 0) ? 0 : ss[t - 1]);
    if (i < NN) {
        row_start[i] = excl;
        cnt_cursor[i] = excl;  // becomes scatter cursor
    }
}

__global__ void scatter_k(const int* __restrict__ srcp, const int* __restrict__ dstp,
                          int* __restrict__ cursor, int* __restrict__ csr_src, int* __restrict__ csr_eid) {
    int e = blockIdx.x * 256 + threadIdx.x;
    if (e >= NE) return;
    int p = atomicAdd(cursor + dstp[e], 1);
    csr_src[p] = srcp[e];
    csr_eid[p] = e;
}

// ---------------- edge MLPs (all 13 convs, CSR order) ----------------

__global__ void pack_weights_k(const float* __restrict__ m1W1, const float* __restrict__ m1b1,
                               const float* __restrict__ m2W1, const float* __restrict__ m2b1,
                               const float* __restrict__ hm1W, const float* __restrict__ hm1b,
                               const float* __restrict__ hm2W, const float* __restrict__ hm2b,
                               float* __restrict__ wbuf) {
    int i = blockIdx.x * 256 + threadIdx.x;
    if (i >= NCONV * 289) return;
    int cc = i / 289, r = i % 289;
    float v;
    if (r < 256)      v = cc ? hm1W[(cc - 1) * 256 + r] : m1W1[r];
    else if (r < 272) v = cc ? hm1b[(cc - 1) * 16 + (r - 256)] : m1b1[r - 256];
    else if (r < 288) v = cc ? hm2W[(cc - 1) * 16 + (r - 272)] : m2W1[r - 272];
    else              v = cc ? hm2b[cc - 1] : m2b1[0];
    wbuf[cc * WSTRIDE + r] = v;
}

__global__ __launch_bounds__(256, 4) void edge_mlp_k(const float* __restrict__ attr, const int* __restrict__ eid_arr,
                                                     const float* __restrict__ wbuf, float* __restrict__ ew) {
    int k = blockIdx.x * 256 + threadIdx.x;
    if (k >= NE) return;
    int eid = eid_arr[k];
    const float4* a4 = (const float4*)(attr + (size_t)eid * 16);
    float4 A0 = a4[0], A1 = a4[1], A2 = a4[2], A3 = a4[3];
    float a[16] = {A0.x, A0.y, A0.z, A0.w, A1.x, A1.y, A1.z, A1.w,
                   A2.x, A2.y, A2.z, A2.w, A3.x, A3.y, A3.z, A3.w};
    for (int cc = 0; cc < NCONV; cc++) {
        const float* wb = wbuf + cc * WSTRIDE;  // uniform address -> s_load
        float hb[16];
        #pragma unroll
        for (int o = 0; o < 16; o++) hb[o] = wb[256 + o];
        #pragma unroll
        for (int i = 0; i < 16; i++) {
            float av = a[i];
            #pragma unroll
            for (int o = 0; o < 16; o++) hb[o] = fmaf(av, wb[i * 16 + o], hb[o]);
        }
        float z = wb[288];
        #pragma unroll
        for (int o = 0; o < 16; o++) {
            float hv = hb[o] > 0.f ? hb[o] : 0.f;
            z = fmaf(hv, wb[272 + o], z);
        }
        ew[(size_t)cc * NE + k] = 1.f / (1.f + __expf(-z));
    }
}

// deg = 1 + sum of incoming ew; dis = rsqrt(deg)  (deg >= 1 always)
__global__ void deg_dis_k(const int* __restrict__ row_start, const float* __restrict__ ew,
                          float* __restrict__ dis) {
    int n = blockIdx.x * 256 + threadIdx.x;
    int cc = blockIdx.y;
    if (n >= NN) return;
    int s0 = row_start[n], s1 = row_start[n + 1];
    const float* e = ew + (size_t)cc * NE;
    float s = 1.f;
    for (int k = s0; k < s1; k++) s += e[k];
    dis[cc * NN + n] = rsqrtf(s);
}

// ---------------- BN stats ----------------

#define BN_BLOCKS 250  // 200 rows each

__global__ __launch_bounds__(256) void bn_part_k(const float* __restrict__ cur, float* __restrict__ part) {
    int c = threadIdx.x & 63, rq = threadIdx.x >> 6;
    int r0 = blockIdx.x * 200;
    float s = 0.f, q = 0.f;
    for (int r = r0 + rq; r < r0 + 200; r += 4) {
        float v = cur[(size_t)r * 64 + c];
        s += v; q = fmaf(v, v, q);
    }
    __shared__ float red[512];
    red[threadIdx.x] = s; red[256 + threadIdx.x] = q;
    __syncthreads();
    if (rq == 0) {
        s = red[c] + red[64 + c] + red[128 + c] + red[192 + c];
        q = red[256 + c] + red[320 + c] + red[384 + c] + red[448 + c];
        part[blockIdx.x * 128 + c] = s;
        part[blockIdx.x * 128 + 64 + c] = q;
    }
}

__global__ void bn_final_k(const float* __restrict__ part, float* __restrict__ bnstats) {
    int c = threadIdx.x;  // 64 threads
    double s = 0.0, q = 0.0;
    for (int b = 0; b < BN_BLOCKS; b++) {
        s += (double)part[b * 128 + c];
        q += (double)part[b * 128 + 64 + c];
    }
    double mu = s / (double)NN;
    double var = q / (double)NN - mu * mu;
    if (var < 0.0) var = 0.0;
    bnstats[c] = (float)mu;
    bnstats[64 + c] = (float)(1.0 / sqrt(var + 1e-5));
}

// ---------------- GEMM: H = bn_relu(X) @ W  (one row per thread, W via s_load) ----------------

template <bool BN>
__global__ __launch_bounds__(256) void gemm_k(const float* __restrict__ X, const float* __restrict__ Wg,
                                              const float* __restrict__ bnstats, float* __restrict__ H) {
    int r = blockIdx.x * 256 + threadIdx.x;
    if (r >= NN) return;
    float acc[64];
    #pragma unroll
    for (int c = 0; c < 64; c++) acc[c] = 0.f;
    const float4* x4 = (const float4*)(X + (size_t)r * 64);
    for (int kq = 0; kq < 16; kq++) {
        float4 xv = x4[kq];
        float xs[4] = {xv.x, xv.y, xv.z, xv.w};
        #pragma unroll
        for (int j = 0; j < 4; j++) {
            int k = kq * 4 + j;
            float v = xs[j];
            if (BN) {
                v = (v - bnstats[k]) * bnstats[64 + k];
                v = v > 0.f ? v : 0.f;
            }
            const float* wr = Wg + k * 64;  // uniform -> SGPR operands
            #pragma unroll
            for (int c = 0; c < 64; c++) acc[c] = fmaf(v, wr[c], acc[c]);
        }
    }
    float4* o4 = (float4*)(H + (size_t)r * 64);
    #pragma unroll
    for (int q = 0; q < 16; q++) {
        float4 t;
        t.x = acc[4 * q]; t.y = acc[4 * q + 1]; t.z = acc[4 * q + 2]; t.w = acc[4 * q + 3];
        o4[q] = t;
    }
}

// ---------------- aggregation: 16 lanes/node, 4 nodes/wave, float4 gathers ----------------
// One dwordx4 gather instruction fetches 4 full rows (1 KB) vs 1 row (256 B) before.
// NN = 50000 = 3125 blocks * 16 nodes exactly -> no bounds guards.
// MODE 0: outv = v                          (odd cj, mid-block)
// MODE 1: outv = v; S = v                   (cj == 0)
// MODE 2: v2 = v + S; outv = v2; S += v2    (end of block, cj = 2,4,6,8,10)
// MODE 3: MODE 2 + relu + pooled atomicMax  (cj == 12, final conv)

template <int MODE>
__global__ __launch_bounds__(256) void aggregate_k(const float* __restrict__ H, const int* __restrict__ row_start,
                                                   const int* __restrict__ csr_src, const float* __restrict__ w,
                                                   const float* __restrict__ dis, const float* __restrict__ bias,
                                                   float* __restrict__ outv, float* __restrict__ S,
                                                   const int* __restrict__ batch, float* __restrict__ pooled) {
    int t = threadIdx.x;
    int wvid = t >> 6;           // wave 0..3
    int lane = t & 63;
    int g = lane >> 4;           // node-group within wave 0..3
    int li = lane & 15;          // lane within group (features 4*li..4*li+3)
    int node = blockIdx.x * 16 + wvid * 4 + g;
    int s0 = row_start[node], s1 = row_start[node + 1];
    float4 acc = {0.f, 0.f, 0.f, 0.f};
    int k = s0;
    for (; k + 2 <= s1; k += 2) {
        int ia = csr_src[k], ib = csr_src[k + 1];
        float wa = w[k] * dis[ia];
        float wb = w[k + 1] * dis[ib];
        float4 ha = *(const float4*)(H + (size_t)ia * 64 + li * 4);
        float4 hb = *(const float4*)(H + (size_t)ib * 64 + li * 4);
        acc.x = fmaf(ha.x, wa, acc.x); acc.y = fmaf(ha.y, wa, acc.y);
        acc.z = fmaf(ha.z, wa, acc.z); acc.w = fmaf(ha.w, wa, acc.w);
        acc.x = fmaf(hb.x, wb, acc.x); acc.y = fmaf(hb.y, wb, acc.y);
        acc.z = fmaf(hb.z, wb, acc.z); acc.w = fmaf(hb.w, wb, acc.w);
    }
    if (k < s1) {
        int ia = csr_src[k];
        float wa = w[k] * dis[ia];
        float4 ha = *(const float4*)(H + (size_t)ia * 64 + li * 4);
        acc.x = fmaf(ha.x, wa, acc.x); acc.y = fmaf(ha.y, wa, acc.y);
        acc.z = fmaf(ha.z, wa, acc.z); acc.w = fmaf(ha.w, wa, acc.w);
    }
    float dn = dis[node];
    float dnn = dn * dn;
    float4 hs = *(const float4*)(H + (size_t)node * 64 + li * 4);
    float4 b4 = *(const float4*)(bias + li * 4);
    float4 v;
    v.x = fmaf(acc.x, dn, fmaf(hs.x, dnn, b4.x));
    v.y = fmaf(acc.y, dn, fmaf(hs.y, dnn, b4.y));
    v.z = fmaf(acc.z, dn, fmaf(hs.z, dnn, b4.z));
    v.w = fmaf(acc.w, dn, fmaf(hs.w, dnn, b4.w));
    size_t oi = (size_t)node * 64 + li * 4;
    if (MODE == 0) {
        *(float4*)(outv + oi) = v;
    } else if (MODE == 1) {
        *(float4*)(outv + oi) = v;
        *(float4*)(S + oi) = v;
    } else {
        float4 s = *(const float4*)(S + oi);
        float4 v2;
        v2.x = v.x + s.x; v2.y = v.y + s.y; v2.z = v.z + s.z; v2.w = v.w + s.w;
        *(float4*)(outv + oi) = v2;
        float4 s2;
        s2.x = s.x + v2.x; s2.y = s.y + v2.y; s2.z = s.z + v2.z; s2.w = s.w + v2.w;
        *(float4*)(S + oi) = s2;
        if (MODE == 3) {
            float* pb = pooled + (size_t)batch[node] * 64 + li * 4;
            float r0 = v2.x > 0.f ? v2.x : 0.f;
            float r1 = v2.y > 0.f ? v2.y : 0.f;
            float r2 = v2.z > 0.f ? v2.z : 0.f;
            float r3 = v2.w > 0.f ? v2.w : 0.f;
            atomicMax((int*)(pb + 0), __float_as_int(r0));
            atomicMax((int*)(pb + 1), __float_as_int(r1));
            atomicMax((int*)(pb + 2), __float_as_int(r2));
            atomicMax((int*)(pb + 3), __float_as_int(r3));
        }
    }
}

__global__ void final_k(const float* __restrict__ pooled, const float* __restrict__ linW,
                        const float* __restrict__ linb, float* __restrict__ outp) {
    int g = blockIdx.x, c = threadIdx.x;  // 64 threads
    float v = pooled[(size_t)g * 64 + c];
    float p0 = v * linW[c * 2 + 0];
    float p1 = v * linW[c * 2 + 1];
    #pragma unroll
    for (int off = 32; off > 0; off >>= 1) {
        p0 += __shfl_down(p0, off, 64);
        p1 += __shfl_down(p1, off, 64);
    }
    if (c == 0) {
        outp[g * 2 + 0] = p0 + linb[0];
        outp[g * 2 + 1] = p1 + linb[1];
    }
}

// ---------------- host ----------------

extern "C" void kernel_launch(void* const* d_in, const int* in_sizes, int n_in,
                              void* d_out, int out_size, void* d_ws, size_t ws_size,
                              hipStream_t stream) {
    const float* x        = (const float*)d_in[0];
    const int*   ei       = (const int*)d_in[1];
    const int*   srcp     = ei;
    const int*   dstp     = ei + NE;
    const int*   batch    = (const int*)d_in[2];
    const float* edge_attr= (const float*)d_in[4];
    const float* Wlin1    = (const float*)d_in[5];
    const float* bias1    = (const float*)d_in[6];
    const float* m1W1     = (const float*)d_in[7];
    const float* m1b1     = (const float*)d_in[8];
    const float* m2W1     = (const float*)d_in[9];
    const float* m2b1     = (const float*)d_in[10];
    const float* hWlin    = (const float*)d_in[11];
    const float* hbias    = (const float*)d_in[12];
    const float* hm1W     = (const float*)d_in[13];
    const float* hm1b     = (const float*)d_in[14];
    const float* hm2W     = (const float*)d_in[15];
    const float* hm2b     = (const float*)d_in[16];
    const float* linW     = (const float*)d_in[17];
    const float* linb     = (const float*)d_in[18];
    float* outp = (float*)d_out;

    char* ws = (char*)d_ws;
    size_t off = 0;
    auto alloc = [&](size_t bytes) -> char* {
        char* p = ws + off;
        off += (bytes + 255) & ~(size_t)255;
        return p;
    };
    int*   cursor   = (int*)alloc((size_t)NN * 4);
    int*   row_start= (int*)alloc((size_t)(NN + 1) * 4);
    int*   csr_src  = (int*)alloc((size_t)NE * 4);
    int*   csr_eid  = (int*)alloc((size_t)NE * 4);
    float* ewbuf    = (float*)alloc((size_t)NCONV * NE * 4);
    float* disbuf   = (float*)alloc((size_t)NCONV * NN * 4);
    float* hbuf     = (float*)alloc((size_t)NN * 64 * 4);
    float* curbuf   = (float*)alloc((size_t)NN * 64 * 4);
    float* Sbuf     = (float*)alloc((size_t)NN * 64 * 4);
    float* part     = (float*)alloc((size_t)BN_BLOCKS * 128 * 4);
    float* bnstats  = (float*)alloc(128 * 4);
    float* pooled   = (float*)alloc((size_t)NG * 64 * 4);
    float* wbuf     = (float*)alloc((size_t)NCONV * WSTRIDE * 4);
    int*   bsum     = (int*)alloc((size_t)SCAN_B * 4);

    const int TB = 256;
    int gN   = (NN + TB - 1) / TB;        // 196
    int gE   = (NE + TB - 1) / TB;        // 3125
    int gA   = NN / 16;                   // 3125 (exact)
    int gW   = (NCONV * 289 + TB - 1) / TB;

    // CSR build
    zero_init_k<<<gN, TB, 0, stream>>>(cursor, pooled);
    count_k<<<gE, TB, 0, stream>>>(dstp, cursor);
    scan_blocksum_k<<<SCAN_B, TB, 0, stream>>>(cursor, bsum);
    scan_bsum_k<<<1, TB, 0, stream>>>(bsum, row_start);
    scan_local_k<<<SCAN_B, TB, 0, stream>>>(cursor, bsum, row_start);
    scatter_k<<<gE, TB, 0, stream>>>(srcp, dstp, cursor, csr_src, csr_eid);

    // edge weights for all 13 convs (raw sigmoid; dis folded in at aggregate time)
    pack_weights_k<<<gW, TB, 0, stream>>>(m1W1, m1b1, m2W1, m2b1, hm1W, hm1b, hm2W, hm2b, wbuf);
    edge_mlp_k<<<gE, TB, 0, stream>>>(edge_attr, csr_eid, wbuf, ewbuf);
    deg_dis_k<<<dim3(gN, NCONV), TB, 0, stream>>>(row_start, ewbuf, disbuf);

    // conv 0 (no BN), then 12 hidden convs
    for (int cj = 0; cj < NCONV; cj++) {
        const float* Win  = (cj == 0) ? Wlin1 : (hWlin + (size_t)(cj - 1) * 4096);
        const float* bin  = (cj == 0) ? bias1 : (hbias + (size_t)(cj - 1) * 64);
        const float* Xin  = (cj == 0) ? x : curbuf;
        if (cj > 0) {
            bn_part_k<<<BN_BLOCKS, TB, 0, stream>>>(curbuf, part);
            bn_final_k<<<1, 64, 0, stream>>>(part, bnstats);
            gemm_k<true><<<gN, TB, 0, stream>>>(Xin, Win, bnstats, hbuf);
        } else {
            gemm_k<false><<<gN, TB, 0, stream>>>(Xin, Win, bnstats, hbuf);
        }
        const float* wcc = ewbuf + (size_t)cj * NE;
        const float* dcc = disbuf + (size_t)cj * NN;
        if (cj == 0)
            aggregate_k<1><<<gA, TB, 0, stream>>>(hbuf, row_start, csr_src, wcc, dcc, bin, curbuf, Sbuf, batch, pooled);
        else if (cj == 12)
            aggregate_k<3><<<gA, TB, 0, stream>>>(hbuf, row_start, csr_src, wcc, dcc, bin, curbuf, Sbuf, batch, pooled);
        else if ((cj & 1) == 0)
            aggregate_k<2><<<gA, TB, 0, stream>>>(hbuf, row_start, csr_src, wcc, dcc, bin, curbuf, Sbuf, batch, pooled);
        else
            aggregate_k<0><<<gA, TB, 0, stream>>>(hbuf, row_start, csr_src, wcc, dcc, bin, curbuf, Sbuf, batch, pooled);
    }

    // readout
    final_k<<<NG, 64, 0, stream>>>(pooled, linW, linb, outp);
}